// Round 7
// baseline (269.791 us; speedup 1.0000x reference)
//
#include <hip/hip_runtime.h>

#define B_ 4
#define C_ 128
#define H_ 128
#define W_ 256
#define HW_ (H_ * W_)
#define ND 81
#define TH 8          // output rows per block
#define TW 16         // output cols per block
#define HR 16         // f2 halo rows  (TH + 8)
#define WCOL 32       // f2 halo cols
#define KC 32         // channels per LDS chunk (= MFMA K)
#define NCHUNK (C_ / KC)
#define NTHREADS 512

typedef short bf16x8 __attribute__((ext_vector_type(8)));
typedef float f32x4 __attribute__((ext_vector_type(4)));
typedef float f32x4v __attribute__((ext_vector_type(4)));

// Swizzle (HW-verified R1/R3-R6): XOR bits 4..6 of the full byte address by
// (r & 7) << 4 where r = px>>1 lives in bits >=7. Bijective.
__device__ __forceinline__ int swz(int px, int byteInHalf) {
    int r = px >> 1;
    int base = (r << 7) + ((px & 1) << 6) + byteInHalf;
    return base ^ ((r & 7) << 4);
}

// Native packed fp32->bf16 convert (gfx950). A/B use the same packing so the
// MFMA dot is invariant to lo/hi order.
__device__ __forceinline__ unsigned int cvt_pk_bf16(float a, float b) {
    unsigned int r;
    asm("v_cvt_pk_bf16_f32 %0, %1, %2" : "=v"(r) : "v"(a), "v"(b));
    return r;
}

// Barrier WITHOUT vmcnt drain: lgkmcnt(0) orders all LDS traffic; global
// loads stay in flight across the barrier (R6-verified safe).
#define BARRIER()                                             \
    do {                                                      \
        asm volatile("s_waitcnt lgkmcnt(0)" ::: "memory");    \
        __builtin_amdgcn_s_barrier();                         \
    } while (0)

__global__ __launch_bounds__(NTHREADS, 4)   // 4 waves/EU -> 2 blocks/CU, VGPR<=128
void corr81_kernel(const float* __restrict__ f1g, const float* __restrict__ f2g,
                   float* __restrict__ out) {
    // Double-buffered staging: exactly 80 KB -> 2 blocks/CU.
    __shared__ __align__(16) unsigned short f2s[2][HR * WCOL * KC];  // 2 x 32 KB
    __shared__ __align__(16) unsigned short f1s[2][TH * TW * KC];    // 2 x 8 KB
    // invn arrays OVERLAY buf0; written after the final loop barrier (all
    // buf0 MFMA reads done at k=2), extra barrier before epilogue reads.
    float* invn2 = (float*)&f2s[0][0];   // 512 floats
    float* invn1 = (float*)&f1s[0][0];   // 128 floats

    const int tid  = threadIdx.x;
    const int lane = tid & 63;
    const int wave = tid >> 6;            // 0..7 -> output row within tile
    const int col  = lane & 15;
    const int quad = lane >> 4;

    // XCD-aware block swizzle (T1, verified R4). Bijective: 1024 = 8*128.
    const int flat = blockIdx.x + 16 * blockIdx.y + 256 * blockIdx.z;
    const int orig = (flat & 7) * 128 + (flat >> 3);
    const int w0 = (orig & 15) * TW;
    const int h0 = ((orig >> 4) & 15) * TH;
    const int b  = orig >> 8;
    const size_t inBase = (size_t)b * C_ * HW_;

    // f2 staging: rows r = i*4+rq (i 0..3), half A = i{0,1}, half B = i{2,3}
    const int g2  = tid & 7;
    const int cp2 = (tid >> 3) & 15;
    const int rq  = tid >> 7;
    const int gw2 = w0 - 4 + g2 * 4;
    const bool colok2 = (gw2 >= 0) && (gw2 < W_);

    // f1 staging: one float4-pair per thread
    const int g1  = tid & 3;
    const int cp1 = (tid >> 2) & 15;
    const int r1  = tid >> 6;
    const float* src1 = f1g + inBase + (size_t)(h0 + r1) * W_ + (w0 + g1 * 4);

    const int aOff = swz(wave * 16 + col, quad * 16);

    f32x4 acc[9][2];
#pragma unroll
    for (int d = 0; d < 9; ++d) {
        acc[d][0] = (f32x4)0.f;
        acc[d][1] = (f32x4)0.f;
    }
    // norm accumulators (diag-MFMA): f2 rows {wave, wave+8} x col-tiles {0,1}
    f32x4 nacc00 = (f32x4)0.f, nacc01 = (f32x4)0.f;
    f32x4 nacc10 = (f32x4)0.f, nacc11 = (f32x4)0.f;
    f32x4 nacc1  = (f32x4)0.f;

    // half-size f2 prefetch regs + f1 prefetch regs
    f32x4v H0[2], H1[2], B0, B1;

#define ISSUE_HALF(kc0, i0)                                                     \
    {                                                                           \
        _Pragma("unroll")                                                       \
        for (int ii = 0; ii < 2; ++ii) {                                        \
            int r  = ((i0) + ii) * 4 + rq;                                      \
            int gh = h0 - 4 + r;                                                \
            if (colok2 && gh >= 0 && gh < H_) {                                 \
                const float* s = f2g + inBase + (size_t)((kc0) + cp2 * 2) * HW_ \
                                 + (size_t)gh * W_ + gw2;                       \
                H0[ii] = *(const f32x4v*)s;                                     \
                H1[ii] = *(const f32x4v*)(s + HW_);                             \
            } else {                                                            \
                H0[ii] = (f32x4v)0.f;                                           \
                H1[ii] = (f32x4v)0.f;                                           \
            }                                                                   \
        }                                                                       \
    }

#define PACK_HALF(buf, i0)                                                      \
    {                                                                           \
        char* w2 = (char*)&f2s[(buf)][0];                                       \
        _Pragma("unroll")                                                       \
        for (int ii = 0; ii < 2; ++ii) {                                        \
            int r = ((i0) + ii) * 4 + rq;                                       \
            _Pragma("unroll")                                                   \
            for (int j = 0; j < 4; ++j) {                                       \
                int px = r * 32 + g2 * 4 + j;                                   \
                *(unsigned int*)(w2 + swz(px, cp2 * 4)) =                       \
                    cvt_pk_bf16(H0[ii][j], H1[ii][j]);                          \
            }                                                                   \
        }                                                                       \
    }

#define ISSUE_F1(kc0)                                                           \
    {                                                                           \
        const float* s = src1 + (size_t)((kc0) + cp1 * 2) * HW_;                \
        B0 = *(const f32x4v*)s;                                                 \
        B1 = *(const f32x4v*)(s + HW_);                                         \
    }

#define PACK_F1(buf)                                                            \
    {                                                                           \
        char* w1 = (char*)&f1s[(buf)][0];                                       \
        _Pragma("unroll")                                                       \
        for (int j = 0; j < 4; ++j) {                                           \
            int px = r1 * 16 + g1 * 4 + j;                                      \
            *(unsigned int*)(w1 + swz(px, cp1 * 4)) = cvt_pk_bf16(B0[j], B1[j]);\
        }                                                                       \
    }

    // MFMA phase: 18 Gram MFMAs + 5 norm-diag MFMAs (reusing loaded frags)
#define MFMA_ALL(buf)                                                           \
    {                                                                           \
        const char* r2  = (const char*)&f2s[(buf)][0];                          \
        const char* r1p = (const char*)&f1s[(buf)][0];                          \
        bf16x8 af = *(const bf16x8*)(r1p + aOff);                               \
        nacc1 = __builtin_amdgcn_mfma_f32_16x16x32_bf16(af, af, nacc1, 0, 0, 0);\
        _Pragma("unroll")                                                       \
        for (int dy = 0; dy < 9; ++dy) {                                        \
            int pb = (wave + dy) * WCOL + col;                                  \
            bf16x8 b0 = *(const bf16x8*)(r2 + swz(pb, quad * 16));              \
            bf16x8 b1 = *(const bf16x8*)(r2 + swz(pb + 16, quad * 16));         \
            acc[dy][0] = __builtin_amdgcn_mfma_f32_16x16x32_bf16(af, b0, acc[dy][0], 0, 0, 0); \
            acc[dy][1] = __builtin_amdgcn_mfma_f32_16x16x32_bf16(af, b1, acc[dy][1], 0, 0, 0); \
            if (dy == 0) {                                                      \
                nacc00 = __builtin_amdgcn_mfma_f32_16x16x32_bf16(b0, b0, nacc00, 0, 0, 0); \
                nacc01 = __builtin_amdgcn_mfma_f32_16x16x32_bf16(b1, b1, nacc01, 0, 0, 0); \
            }                                                                   \
            if (dy == 8) {                                                      \
                nacc10 = __builtin_amdgcn_mfma_f32_16x16x32_bf16(b0, b0, nacc10, 0, 0, 0); \
                nacc11 = __builtin_amdgcn_mfma_f32_16x16x32_bf16(b1, b1, nacc11, 0, 0, 0); \
            }                                                                   \
        }                                                                       \
    }

    // STAGE(k): write chunk k+1 into buf bk^1; A-half/f1 regs carry
    // cross-interval flight, B-half is issued+consumed intra-interval.
#define STAGE(k, bufnext)                                                       \
    if ((k) < NCHUNK - 1) {                                                     \
        PACK_HALF((bufnext), 0);                                                \
        ISSUE_HALF(((k) + 1) * KC, 2);                                          \
        PACK_F1((bufnext));                                                     \
        PACK_HALF((bufnext), 2);                                                \
        if ((k) < NCHUNK - 2) {                                                 \
            ISSUE_HALF(((k) + 2) * KC, 0);                                      \
            ISSUE_F1(((k) + 2) * KC);                                           \
        }                                                                       \
    }

    // ---- prologue: stage chunk 0 into buf0; prefetch chunk 1 A-half + f1 ----
    ISSUE_HALF(0, 0);
    ISSUE_F1(0);
    PACK_HALF(0, 0);
    PACK_F1(0);
    ISSUE_HALF(0, 2);
    PACK_HALF(0, 2);
    ISSUE_HALF(KC, 0);
    ISSUE_F1(KC);
    BARRIER();

    // ---- main loop: wave-parity phase stagger breaks pipe lockstep ----
    for (int k = 0; k < NCHUNK; ++k) {
        const int bk = k & 1;
        if (wave & 1) {
            STAGE(k, bk ^ 1);
            MFMA_ALL(bk);
        } else {
            MFMA_ALL(bk);
            STAGE(k, bk ^ 1);
        }
        BARRIER();
    }

    // ---- norms from diag(nacc): lane holds D[row][col], diag where
    // col == quad*4+r (verified C/D mapping) ----
#pragma unroll
    for (int r = 0; r < 4; ++r) {
        if (col == quad * 4 + r) {
            invn2[wave * 32 + col]           = 1.f / fmaxf(sqrtf(nacc00[r]), 1e-12f);
            invn2[wave * 32 + 16 + col]      = 1.f / fmaxf(sqrtf(nacc01[r]), 1e-12f);
            invn2[(wave + 8) * 32 + col]     = 1.f / fmaxf(sqrtf(nacc10[r]), 1e-12f);
            invn2[(wave + 8) * 32 + 16 + col] = 1.f / fmaxf(sqrtf(nacc11[r]), 1e-12f);
            invn1[wave * 16 + col]           = 1.f / fmaxf(sqrtf(nacc1[r]), 1e-12f);
        }
    }
    BARRIER();

    // ---- epilogue: extract band, rescale, leaky-relu, store ----
    const int hOut = h0 + wave;
    float* outB = out + (size_t)b * ND * HW_ + (size_t)hOut * W_;
    const float scale = 1.f / (float)C_;

#pragma unroll
    for (int dy = 0; dy < 9; ++dy) {
        int hr = wave + dy;
#pragma unroll
        for (int t = 0; t < 2; ++t) {
            float i2 = invn2[hr * WCOL + t * 16 + col];
#pragma unroll
            for (int r = 0; r < 4; ++r) {
                int row = quad * 4 + r;
                int dx = t * 16 + col - row;
                if (dx >= 0 && dx <= 8) {
                    float v = acc[dy][t][r] * invn1[wave * 16 + row] * i2 * scale;
                    v = (v >= 0.f) ? v : 0.1f * v;
                    outB[(size_t)(dy * 9 + dx) * HW_ + (w0 + row)] = v;
                }
            }
        }
    }
#undef ISSUE_HALF
#undef PACK_HALF
#undef ISSUE_F1
#undef PACK_F1
#undef MFMA_ALL
#undef STAGE
}

extern "C" void kernel_launch(void* const* d_in, const int* in_sizes, int n_in,
                              void* d_out, int out_size, void* d_ws, size_t ws_size,
                              hipStream_t stream) {
    const float* f1 = (const float*)d_in[0];
    const float* f2 = (const float*)d_in[1];
    float* out = (float*)d_out;
    dim3 grid(W_ / TW, H_ / TH, B_);   // 16 x 16 x 4 = 1024 blocks
    corr81_kernel<<<grid, NTHREADS, 0, stream>>>(f1, f2, out);
}

// Round 8
// 101.230 us; speedup vs baseline: 2.6651x; 2.6651x over previous
//
#include <hip/hip_runtime.h>

#define B_ 4
#define C_ 128
#define H_ 128
#define W_ 256
#define HW_ (H_ * W_)
#define ND 81
#define TH 8          // output rows per block
#define TW 16         // output cols per block
#define HR 16         // f2 halo rows  (TH + 8)
#define WCOL 32       // f2 halo cols
#define KC 32         // channels per LDS chunk (= MFMA K)
#define NCHUNK (C_ / KC)
#define NTHREADS 512

typedef short bf16x8 __attribute__((ext_vector_type(8)));
typedef float f32x4 __attribute__((ext_vector_type(4)));
typedef float f32x4v __attribute__((ext_vector_type(4)));

// Swizzle (HW-verified R1/R3-R6): XOR bits 4..6 of the full byte address by
// (r & 7) << 4 where r = px>>1 lives in bits >=7. Bijective.
__device__ __forceinline__ int swz(int px, int byteInHalf) {
    int r = px >> 1;
    int base = (r << 7) + ((px & 1) << 6) + byteInHalf;
    return base ^ ((r & 7) << 4);
}

// Native packed fp32->bf16 convert (gfx950). A/B use the same packing so the
// MFMA dot is invariant to lo/hi order.
__device__ __forceinline__ unsigned int cvt_pk_bf16(float a, float b) {
    unsigned int r;
    asm("v_cvt_pk_bf16_f32 %0, %1, %2" : "=v"(r) : "v"(a), "v"(b));
    return r;
}

// Barrier WITHOUT vmcnt drain: lgkmcnt(0) orders all LDS traffic; global
// loads stay in flight across the barrier (R6-verified safe).
#define BARRIER()                                             \
    do {                                                      \
        asm volatile("s_waitcnt lgkmcnt(0)" ::: "memory");    \
        __builtin_amdgcn_s_barrier();                         \
    } while (0)

// NOTE R7 erratum: hipcc treats the 2nd launch_bounds arg as min BLOCKS/CU
// (CUDA semantics) here — arg=4 capped VGPR at 64 and spilled catastrophically.
// arg=2 -> VGPR cap 128 = exactly the 2-blocks/CU design point (LDS 80KB
// already limits to 2 blocks/CU).
__global__ __launch_bounds__(NTHREADS, 2)
void corr81_kernel(const float* __restrict__ f1g, const float* __restrict__ f2g,
                   float* __restrict__ out) {
    // Double-buffered staging: exactly 80 KB -> 2 blocks/CU.
    __shared__ __align__(16) unsigned short f2s[2][HR * WCOL * KC];  // 2 x 32 KB
    __shared__ __align__(16) unsigned short f1s[2][TH * TW * KC];    // 2 x 8 KB
    // invn arrays OVERLAY buf0; written after the final loop barrier, extra
    // barrier before epilogue reads.
    float* invn2 = (float*)&f2s[0][0];   // 512 floats
    float* invn1 = (float*)&f1s[0][0];   // 128 floats

    const int tid  = threadIdx.x;
    const int lane = tid & 63;
    const int wave = tid >> 6;            // 0..7 -> output row within tile
    const int col  = lane & 15;
    const int quad = lane >> 4;

    // XCD-aware block swizzle (T1, verified R4). Bijective: 1024 = 8*128.
    const int flat = blockIdx.x + 16 * blockIdx.y + 256 * blockIdx.z;
    const int orig = (flat & 7) * 128 + (flat >> 3);
    const int w0 = (orig & 15) * TW;
    const int h0 = ((orig >> 4) & 15) * TH;
    const int b  = orig >> 8;
    const size_t inBase = (size_t)b * C_ * HW_;

    // f2 staging: rows r = i*4+rq (i 0..3), half A = i{0,1}, half B = i{2,3}
    const int g2  = tid & 7;
    const int cp2 = (tid >> 3) & 15;
    const int rq  = tid >> 7;
    const int gw2 = w0 - 4 + g2 * 4;
    const bool colok2 = (gw2 >= 0) && (gw2 < W_);

    // f1 staging: one float4-pair per thread
    const int g1  = tid & 3;
    const int cp1 = (tid >> 2) & 15;
    const int r1  = tid >> 6;
    const float* src1 = f1g + inBase + (size_t)(h0 + r1) * W_ + (w0 + g1 * 4);

    const int aOff = swz(wave * 16 + col, quad * 16);

    f32x4 acc[9][2];
#pragma unroll
    for (int d = 0; d < 9; ++d) {
        acc[d][0] = (f32x4)0.f;
        acc[d][1] = (f32x4)0.f;
    }
    // norm accumulators (diag-MFMA): f2 rows {wave, wave+8} x col-tiles {0,1}
    f32x4 nacc00 = (f32x4)0.f, nacc01 = (f32x4)0.f;
    f32x4 nacc10 = (f32x4)0.f, nacc11 = (f32x4)0.f;
    f32x4 nacc1  = (f32x4)0.f;

    // half-size f2 prefetch regs + f1 prefetch regs
    f32x4v H0[2], H1[2], B0, B1;

#define ISSUE_HALF(kc0, i0)                                                     \
    {                                                                           \
        _Pragma("unroll")                                                       \
        for (int ii = 0; ii < 2; ++ii) {                                        \
            int r  = ((i0) + ii) * 4 + rq;                                      \
            int gh = h0 - 4 + r;                                                \
            if (colok2 && gh >= 0 && gh < H_) {                                 \
                const float* s = f2g + inBase + (size_t)((kc0) + cp2 * 2) * HW_ \
                                 + (size_t)gh * W_ + gw2;                       \
                H0[ii] = *(const f32x4v*)s;                                     \
                H1[ii] = *(const f32x4v*)(s + HW_);                             \
            } else {                                                            \
                H0[ii] = (f32x4v)0.f;                                           \
                H1[ii] = (f32x4v)0.f;                                           \
            }                                                                   \
        }                                                                       \
    }

#define PACK_HALF(buf, i0)                                                      \
    {                                                                           \
        char* w2 = (char*)&f2s[(buf)][0];                                       \
        _Pragma("unroll")                                                       \
        for (int ii = 0; ii < 2; ++ii) {                                        \
            int r = ((i0) + ii) * 4 + rq;                                       \
            _Pragma("unroll")                                                   \
            for (int j = 0; j < 4; ++j) {                                       \
                int px = r * 32 + g2 * 4 + j;                                   \
                *(unsigned int*)(w2 + swz(px, cp2 * 4)) =                       \
                    cvt_pk_bf16(H0[ii][j], H1[ii][j]);                          \
            }                                                                   \
        }                                                                       \
    }

#define ISSUE_F1(kc0)                                                           \
    {                                                                           \
        const float* s = src1 + (size_t)((kc0) + cp1 * 2) * HW_;                \
        B0 = *(const f32x4v*)s;                                                 \
        B1 = *(const f32x4v*)(s + HW_);                                         \
    }

#define PACK_F1(buf)                                                            \
    {                                                                           \
        char* w1 = (char*)&f1s[(buf)][0];                                       \
        _Pragma("unroll")                                                       \
        for (int j = 0; j < 4; ++j) {                                           \
            int px = r1 * 16 + g1 * 4 + j;                                      \
            *(unsigned int*)(w1 + swz(px, cp1 * 4)) = cvt_pk_bf16(B0[j], B1[j]);\
        }                                                                       \
    }

    // MFMA phase: 18 Gram MFMAs + 5 norm-diag MFMAs (reusing loaded frags)
#define MFMA_ALL(buf)                                                           \
    {                                                                           \
        const char* r2  = (const char*)&f2s[(buf)][0];                          \
        const char* r1p = (const char*)&f1s[(buf)][0];                          \
        bf16x8 af = *(const bf16x8*)(r1p + aOff);                               \
        nacc1 = __builtin_amdgcn_mfma_f32_16x16x32_bf16(af, af, nacc1, 0, 0, 0);\
        _Pragma("unroll")                                                       \
        for (int dy = 0; dy < 9; ++dy) {                                        \
            int pb = (wave + dy) * WCOL + col;                                  \
            bf16x8 b0 = *(const bf16x8*)(r2 + swz(pb, quad * 16));              \
            bf16x8 b1 = *(const bf16x8*)(r2 + swz(pb + 16, quad * 16));         \
            acc[dy][0] = __builtin_amdgcn_mfma_f32_16x16x32_bf16(af, b0, acc[dy][0], 0, 0, 0); \
            acc[dy][1] = __builtin_amdgcn_mfma_f32_16x16x32_bf16(af, b1, acc[dy][1], 0, 0, 0); \
            if (dy == 0) {                                                      \
                nacc00 = __builtin_amdgcn_mfma_f32_16x16x32_bf16(b0, b0, nacc00, 0, 0, 0); \
                nacc01 = __builtin_amdgcn_mfma_f32_16x16x32_bf16(b1, b1, nacc01, 0, 0, 0); \
            }                                                                   \
            if (dy == 8) {                                                      \
                nacc10 = __builtin_amdgcn_mfma_f32_16x16x32_bf16(b0, b0, nacc10, 0, 0, 0); \
                nacc11 = __builtin_amdgcn_mfma_f32_16x16x32_bf16(b1, b1, nacc11, 0, 0, 0); \
            }                                                                   \
        }                                                                       \
    }

    // STAGE(k): write chunk k+1 into buf bk^1; A-half/f1 regs carry
    // cross-interval flight, B-half is issued+consumed intra-interval.
#define STAGE(k, bufnext)                                                       \
    if ((k) < NCHUNK - 1) {                                                     \
        PACK_HALF((bufnext), 0);                                                \
        ISSUE_HALF(((k) + 1) * KC, 2);                                          \
        PACK_F1((bufnext));                                                     \
        PACK_HALF((bufnext), 2);                                                \
        if ((k) < NCHUNK - 2) {                                                 \
            ISSUE_HALF(((k) + 2) * KC, 0);                                      \
            ISSUE_F1(((k) + 2) * KC);                                           \
        }                                                                       \
    }

    // ---- prologue: stage chunk 0 into buf0; prefetch chunk 1 A-half + f1 ----
    ISSUE_HALF(0, 0);
    ISSUE_F1(0);
    PACK_HALF(0, 0);
    PACK_F1(0);
    ISSUE_HALF(0, 2);
    PACK_HALF(0, 2);
    ISSUE_HALF(KC, 0);
    ISSUE_F1(KC);
    BARRIER();

    // ---- main loop: wave-parity phase stagger breaks pipe lockstep ----
    for (int k = 0; k < NCHUNK; ++k) {
        const int bk = k & 1;
        if (wave & 1) {
            STAGE(k, bk ^ 1);
            MFMA_ALL(bk);
        } else {
            MFMA_ALL(bk);
            STAGE(k, bk ^ 1);
        }
        BARRIER();
    }

    // ---- norms from diag(nacc): lane holds D[row][col], diag where
    // col == quad*4+r (verified C/D mapping) ----
#pragma unroll
    for (int r = 0; r < 4; ++r) {
        if (col == quad * 4 + r) {
            invn2[wave * 32 + col]            = 1.f / fmaxf(sqrtf(nacc00[r]), 1e-12f);
            invn2[wave * 32 + 16 + col]       = 1.f / fmaxf(sqrtf(nacc01[r]), 1e-12f);
            invn2[(wave + 8) * 32 + col]      = 1.f / fmaxf(sqrtf(nacc10[r]), 1e-12f);
            invn2[(wave + 8) * 32 + 16 + col] = 1.f / fmaxf(sqrtf(nacc11[r]), 1e-12f);
            invn1[wave * 16 + col]            = 1.f / fmaxf(sqrtf(nacc1[r]), 1e-12f);
        }
    }
    BARRIER();

    // ---- epilogue: extract band, rescale, leaky-relu, store ----
    const int hOut = h0 + wave;
    float* outB = out + (size_t)b * ND * HW_ + (size_t)hOut * W_;
    const float scale = 1.f / (float)C_;

#pragma unroll
    for (int dy = 0; dy < 9; ++dy) {
        int hr = wave + dy;
#pragma unroll
        for (int t = 0; t < 2; ++t) {
            float i2 = invn2[hr * WCOL + t * 16 + col];
#pragma unroll
            for (int r = 0; r < 4; ++r) {
                int row = quad * 4 + r;
                int dx = t * 16 + col - row;
                if (dx >= 0 && dx <= 8) {
                    float v = acc[dy][t][r] * invn1[wave * 16 + row] * i2 * scale;
                    v = (v >= 0.f) ? v : 0.1f * v;
                    outB[(size_t)(dy * 9 + dx) * HW_ + (w0 + row)] = v;
                }
            }
        }
    }
#undef ISSUE_HALF
#undef PACK_HALF
#undef ISSUE_F1
#undef PACK_F1
#undef MFMA_ALL
#undef STAGE
}

extern "C" void kernel_launch(void* const* d_in, const int* in_sizes, int n_in,
                              void* d_out, int out_size, void* d_ws, size_t ws_size,
                              hipStream_t stream) {
    const float* f1 = (const float*)d_in[0];
    const float* f2 = (const float*)d_in[1];
    float* out = (float*)d_out;
    dim3 grid(W_ / TW, H_ / TH, B_);   // 16 x 16 x 4 = 1024 blocks
    corr81_kernel<<<grid, NTHREADS, 0, stream>>>(f1, f2, out);
}

// Round 9
// 92.534 us; speedup vs baseline: 2.9156x; 1.0940x over previous
//
#include <hip/hip_runtime.h>

#define B_ 4
#define C_ 128
#define H_ 128
#define W_ 256
#define HW_ (H_ * W_)
#define ND 81
#define TH 8          // output rows per block
#define TW 16         // output cols per block
#define HR 16         // f2 halo rows  (TH + 8)
#define WCOL 32       // f2 halo cols
#define KC 32         // channels per LDS chunk (= MFMA K)
#define NCHUNK (C_ / KC)
#define NTHREADS 512

typedef short bf16x8 __attribute__((ext_vector_type(8)));
typedef float f32x4 __attribute__((ext_vector_type(4)));
typedef float f32x4v __attribute__((ext_vector_type(4)));
typedef unsigned int u32x4 __attribute__((ext_vector_type(4)));

// Swizzle (HW-verified R1/R3-R6): XOR bits 4..6 of the full byte address by
// (r & 7) << 4 where r = px>>1 lives in bits >=7. Bijective.
__device__ __forceinline__ int swz(int px, int byteInHalf) {
    int r = px >> 1;
    int base = (r << 7) + ((px & 1) << 6) + byteInHalf;
    return base ^ ((r & 7) << 4);
}

// Native packed fp32->bf16 convert (gfx950). A/B use the same packing so the
// MFMA dot is invariant to lo/hi order.
__device__ __forceinline__ unsigned int cvt_pk_bf16(float a, float b) {
    unsigned int r;
    asm("v_cvt_pk_bf16_f32 %0, %1, %2" : "=v"(r) : "v"(a), "v"(b));
    return r;
}

__device__ __forceinline__ void accum_sq(unsigned int u, float& ss) {
    float lo = __uint_as_float(u << 16);
    float hi = __uint_as_float(u & 0xFFFF0000u);
    ss += lo * lo + hi * hi;
}

// Barrier WITHOUT vmcnt drain: lgkmcnt(0) orders all LDS traffic; global
// loads stay in flight across the barrier (R6-verified safe).
#define BARRIER()                                             \
    do {                                                      \
        asm volatile("s_waitcnt lgkmcnt(0)" ::: "memory");    \
        __builtin_amdgcn_s_barrier();                         \
    } while (0)

// R7/R8 erratum: do NOT pass a min-blocks hint — hipcc applied CUDA
// min-blocks semantics and either capped VGPR at 64 (R7, catastrophic spill)
// or at 128 under over-demand (R8, moderate spill). Plain bound let the
// compiler settle at 124 with zero spill (R6-verified).
__global__ __launch_bounds__(NTHREADS)
void corr81_kernel(const float* __restrict__ f1g, const float* __restrict__ f2g,
                   float* __restrict__ out) {
    // Double-buffered staging: exactly 80 KB -> 2 blocks/CU.
    __shared__ __align__(16) unsigned short f2s[2][HR * WCOL * KC];  // 2 x 32 KB
    __shared__ __align__(16) unsigned short f1s[2][TH * TW * KC];    // 2 x 8 KB
    // invn arrays OVERLAY buf0 (hazard-free: buf0 last staged at k=1, last
    // read at k=2; invn written at k=3 after k=2's barrier; epilogue reads
    // after the final barrier).
    float* invn2 = (float*)&f2s[0][0];   // 512 floats
    float* invn1 = (float*)&f1s[0][0];   // 128 floats

    const int tid  = threadIdx.x;
    const int lane = tid & 63;
    const int wave = tid >> 6;            // 0..7 -> output row within tile
    const int col  = lane & 15;
    const int quad = lane >> 4;

    // XCD-aware block swizzle (T1, verified R4). Bijective: 1024 = 8*128.
    const int flat = blockIdx.x + 16 * blockIdx.y + 256 * blockIdx.z;
    const int orig = (flat & 7) * 128 + (flat >> 3);
    const int w0 = (orig & 15) * TW;
    const int h0 = ((orig >> 4) & 15) * TH;
    const int b  = orig >> 8;
    const size_t inBase = (size_t)b * C_ * HW_;

    // f2 staging: (i 0..3) x per-thread (g2, cp2, rq)
    const int g2  = tid & 7;
    const int cp2 = (tid >> 3) & 15;
    const int rq  = tid >> 7;
    const int gw2 = w0 - 4 + g2 * 4;
    const bool colok2 = (gw2 >= 0) && (gw2 < W_);

    // f1 staging: one float4-pair per thread
    const int g1  = tid & 3;
    const int cp1 = (tid >> 2) & 15;
    const int r1  = tid >> 6;
    const float* src1 = f1g + inBase + (size_t)(h0 + r1) * W_ + (w0 + g1 * 4);

    const int aOff = swz(wave * 16 + col, quad * 16);

    f32x4 acc[9][2];
#pragma unroll
    for (int d = 0; d < 9; ++d) {
        acc[d][0] = (f32x4)0.f;
        acc[d][1] = (f32x4)0.f;
    }

    float ss2 = 0.f, ss1 = 0.f;
    f32x4v A0[4], A1[4], B0, B1;

#define ISSUE_LOADS(kc0)                                                        \
    {                                                                           \
        _Pragma("unroll")                                                       \
        for (int i = 0; i < 4; ++i) {                                           \
            int r  = i * 4 + rq;                                                \
            int gh = h0 - 4 + r;                                                \
            if (colok2 && gh >= 0 && gh < H_) {                                 \
                const float* s = f2g + inBase + (size_t)((kc0) + cp2 * 2) * HW_ \
                                 + (size_t)gh * W_ + gw2;                       \
                A0[i] = *(const f32x4v*)s;                                      \
                A1[i] = *(const f32x4v*)(s + HW_);                              \
            } else {                                                            \
                A0[i] = (f32x4v)0.f;                                            \
                A1[i] = (f32x4v)0.f;                                            \
            }                                                                   \
        }                                                                       \
        const float* s = src1 + (size_t)((kc0) + cp1 * 2) * HW_;                \
        B0 = *(const f32x4v*)s;                                                 \
        B1 = *(const f32x4v*)(s + HW_);                                         \
    }

#define PACK_WRITE(buf)                                                         \
    {                                                                           \
        char* w2 = (char*)&f2s[(buf)][0];                                       \
        char* w1 = (char*)&f1s[(buf)][0];                                       \
        _Pragma("unroll")                                                       \
        for (int i = 0; i < 4; ++i) {                                           \
            int r = i * 4 + rq;                                                 \
            _Pragma("unroll")                                                   \
            for (int j = 0; j < 4; ++j) {                                       \
                int px = r * 32 + g2 * 4 + j;                                   \
                *(unsigned int*)(w2 + swz(px, cp2 * 4)) =                       \
                    cvt_pk_bf16(A0[i][j], A1[i][j]);                            \
            }                                                                   \
        }                                                                       \
        _Pragma("unroll")                                                       \
        for (int j = 0; j < 4; ++j) {                                           \
            int px = r1 * 16 + g1 * 4 + j;                                      \
            *(unsigned int*)(w1 + swz(px, cp1 * 4)) = cvt_pk_bf16(B0[j], B1[j]);\
        }                                                                       \
    }

#define MFMA_PHASE(buf)                                                         \
    {                                                                           \
        const char* r2 = (const char*)&f2s[(buf)][0];                           \
        const char* r1p = (const char*)&f1s[(buf)][0];                          \
        bf16x8 af = *(const bf16x8*)(r1p + aOff);                               \
        _Pragma("unroll")                                                       \
        for (int dy = 0; dy < 9; ++dy) {                                        \
            int pb = (wave + dy) * WCOL + col;                                  \
            bf16x8 b0 = *(const bf16x8*)(r2 + swz(pb, quad * 16));              \
            bf16x8 b1 = *(const bf16x8*)(r2 + swz(pb + 16, quad * 16));         \
            acc[dy][0] = __builtin_amdgcn_mfma_f32_16x16x32_bf16(af, b0, acc[dy][0], 0, 0, 0); \
            acc[dy][1] = __builtin_amdgcn_mfma_f32_16x16x32_bf16(af, b1, acc[dy][1], 0, 0, 0); \
        }                                                                       \
    }

#define NORM_PHASE(buf)                                                         \
    {                                                                           \
        const char* r2 = (const char*)&f2s[(buf)][0];                           \
        const char* r1p = (const char*)&f1s[(buf)][0];                          \
        _Pragma("unroll")                                                       \
        for (int j = 0; j < 4; ++j) {                                           \
            u32x4 v = *(const u32x4*)(r2 + swz(tid, j * 16));                   \
            accum_sq(v[0], ss2); accum_sq(v[1], ss2);                           \
            accum_sq(v[2], ss2); accum_sq(v[3], ss2);                           \
        }                                                                       \
        u32x4 v = *(const u32x4*)(r1p + swz(tid >> 2, (tid & 3) * 16));         \
        accum_sq(v[0], ss1); accum_sq(v[1], ss1);                               \
        accum_sq(v[2], ss1); accum_sq(v[3], ss1);                               \
    }

    // ---- prologue: stage chunk 0 into buf0, issue chunk-1 loads ----
    ISSUE_LOADS(0);
    PACK_WRITE(0);
    ISSUE_LOADS(KC);
    BARRIER();

    // ---- main loop: ONE variable vs R6 — wave-parity phase stagger.
    // Odd waves stage-then-MFMA, even waves MFMA-then-stage: at any instant
    // half the block feeds VALU/VMEM while half feeds LDS-read/MFMA,
    // converting sum-of-pipes toward max-of-pipes. Wave-uniform branch
    // (s_cbranch on SGPR), no divergence. Buffer safety: staging writes
    // bk^1 while MFMA reads bk; lgkmcnt(0)+barrier orders both.
#pragma unroll
    for (int k = 0; k < NCHUNK; ++k) {
        const int bk = k & 1;
        if (k < NCHUNK - 1) {
            if (wave & 1) {
                PACK_WRITE(bk ^ 1);
                if (k < NCHUNK - 2) ISSUE_LOADS((k + 2) * KC);
                MFMA_PHASE(bk);
            } else {
                MFMA_PHASE(bk);
                PACK_WRITE(bk ^ 1);
                if (k < NCHUNK - 2) ISSUE_LOADS((k + 2) * KC);
            }
            NORM_PHASE(bk);
        } else {
            MFMA_PHASE(bk);
            NORM_PHASE(bk);
            invn2[tid] = 1.f / fmaxf(sqrtf(ss2), 1e-12f);
            float t1 = ss1 + __shfl_xor(ss1, 1);
            t1 += __shfl_xor(t1, 2);
            if ((tid & 3) == 0) invn1[tid >> 2] = 1.f / fmaxf(sqrtf(t1), 1e-12f);
        }
        BARRIER();
    }

    // ---- epilogue: extract band, rescale, leaky-relu, store ----
    const int hOut = h0 + wave;
    float* outB = out + (size_t)b * ND * HW_ + (size_t)hOut * W_;
    const float scale = 1.f / (float)C_;

#pragma unroll
    for (int dy = 0; dy < 9; ++dy) {
        int hr = wave + dy;
#pragma unroll
        for (int t = 0; t < 2; ++t) {
            float i2 = invn2[hr * WCOL + t * 16 + col];
#pragma unroll
            for (int r = 0; r < 4; ++r) {
                int row = quad * 4 + r;
                int dx = t * 16 + col - row;
                if (dx >= 0 && dx <= 8) {
                    float v = acc[dy][t][r] * invn1[wave * 16 + row] * i2 * scale;
                    v = (v >= 0.f) ? v : 0.1f * v;
                    outB[(size_t)(dy * 9 + dx) * HW_ + (w0 + row)] = v;
                }
            }
        }
    }
#undef ISSUE_LOADS
#undef PACK_WRITE
#undef MFMA_PHASE
#undef NORM_PHASE
}

extern "C" void kernel_launch(void* const* d_in, const int* in_sizes, int n_in,
                              void* d_out, int out_size, void* d_ws, size_t ws_size,
                              hipStream_t stream) {
    const float* f1 = (const float*)d_in[0];
    const float* f2 = (const float*)d_in[1];
    float* out = (float*)d_out;
    dim3 grid(W_ / TW, H_ / TH, B_);   // 16 x 16 x 4 = 1024 blocks
    corr81_kernel<<<grid, NTHREADS, 0, stream>>>(f1, f2, out);
}

// Round 10
// 64.216 us; speedup vs baseline: 4.2013x; 1.4410x over previous
//
#include <hip/hip_runtime.h>

#define B_ 4
#define C_ 128
#define H_ 128
#define W_ 256
#define HW_ (H_ * W_)
#define ND 81
#define TH 8          // output rows per block
#define TW 16         // output cols per block
#define HR 16         // f2 halo rows  (TH + 8)
#define WCOL 32       // f2 halo cols
#define KC 32         // channels per LDS chunk (= MFMA K)
#define NCHUNK (C_ / KC)
#define NTHREADS 512

typedef short bf16x8 __attribute__((ext_vector_type(8)));
typedef float f32x4 __attribute__((ext_vector_type(4)));
typedef float f32x4v __attribute__((ext_vector_type(4)));
typedef unsigned int u32x4 __attribute__((ext_vector_type(4)));

// Swizzle (HW-verified R1/R3-R6): XOR bits 4..6 of the full byte address by
// (r & 7) << 4 where r = px>>1 lives in bits >=7. Bijective.
__device__ __forceinline__ int swz(int px, int byteInHalf) {
    int r = px >> 1;
    int base = (r << 7) + ((px & 1) << 6) + byteInHalf;
    return base ^ ((r & 7) << 4);
}

// Native packed fp32->bf16 convert (gfx950). A/B use the same packing so the
// MFMA dot is invariant to lo/hi order.
__device__ __forceinline__ unsigned int cvt_pk_bf16(float a, float b) {
    unsigned int r;
    asm("v_cvt_pk_bf16_f32 %0, %1, %2" : "=v"(r) : "v"(a), "v"(b));
    return r;
}

// VOP3P packed bf16 dot: ss += u.lo^2 + u.hi^2 in ONE VALU instruction
// (replaces 2 unpack + 2 FMA of the old accum_sq — the NORM VALU hog).
__device__ __forceinline__ void dot2_sq(unsigned int u, float& ss) {
    asm("v_dot2_f32_bf16 %0, %1, %1, %0" : "+v"(ss) : "v"(u));
}

// Barrier WITHOUT vmcnt drain: lgkmcnt(0) orders all LDS traffic; global
// loads stay in flight across the barrier (R6-verified safe).
#define BARRIER()                                             \
    do {                                                      \
        asm volatile("s_waitcnt lgkmcnt(0)" ::: "memory");    \
        __builtin_amdgcn_s_barrier();                         \
    } while (0)

// R7/R8/R9 errata: no min-blocks hint (CUDA blocks/CU semantics capped VGPR
// catastrophically), and no wave-parity stagger (duplicated phase bodies
// push allocator demand past the 128 cliff -> scratch spill, R9).
__global__ __launch_bounds__(NTHREADS)
void corr81_kernel(const float* __restrict__ f1g, const float* __restrict__ f2g,
                   float* __restrict__ out) {
    // Double-buffered staging: exactly 80 KB -> 2 blocks/CU.
    __shared__ __align__(16) unsigned short f2s[2][HR * WCOL * KC];  // 2 x 32 KB
    __shared__ __align__(16) unsigned short f1s[2][TH * TW * KC];    // 2 x 8 KB
    // invn arrays OVERLAY buf0 (hazard-free: buf0 last staged at k=1, last
    // read at k=2; invn written at k=3 after k=2's barrier; epilogue reads
    // after the final barrier).
    float* invn2 = (float*)&f2s[0][0];   // 512 floats
    float* invn1 = (float*)&f1s[0][0];   // 128 floats

    const int tid  = threadIdx.x;
    const int lane = tid & 63;
    const int wave = tid >> 6;            // 0..7 -> output row within tile
    const int col  = lane & 15;
    const int quad = lane >> 4;

    // XCD-aware block swizzle (T1, verified R4). Bijective: 1024 = 8*128.
    const int flat = blockIdx.x + 16 * blockIdx.y + 256 * blockIdx.z;
    const int orig = (flat & 7) * 128 + (flat >> 3);
    const int w0 = (orig & 15) * TW;
    const int h0 = ((orig >> 4) & 15) * TH;
    const int b  = orig >> 8;
    const size_t inBase = (size_t)b * C_ * HW_;

    // f2 staging: (i 0..3) x per-thread (g2, cp2, rq)
    const int g2  = tid & 7;
    const int cp2 = (tid >> 3) & 15;
    const int rq  = tid >> 7;
    const int gw2 = w0 - 4 + g2 * 4;
    const bool colok2 = (gw2 >= 0) && (gw2 < W_);

    // f1 staging: one float4-pair per thread
    const int g1  = tid & 3;
    const int cp1 = (tid >> 2) & 15;
    const int r1  = tid >> 6;
    const float* src1 = f1g + inBase + (size_t)(h0 + r1) * W_ + (w0 + g1 * 4);

    const int aOff = swz(wave * 16 + col, quad * 16);

    f32x4 acc[9][2];
#pragma unroll
    for (int d = 0; d < 9; ++d) {
        acc[d][0] = (f32x4)0.f;
        acc[d][1] = (f32x4)0.f;
    }

    float ss2 = 0.f, ss1 = 0.f;
    f32x4v A0[4], A1[4], B0, B1;

#define ISSUE_LOADS(kc0)                                                        \
    {                                                                           \
        _Pragma("unroll")                                                       \
        for (int i = 0; i < 4; ++i) {                                           \
            int r  = i * 4 + rq;                                                \
            int gh = h0 - 4 + r;                                                \
            if (colok2 && gh >= 0 && gh < H_) {                                 \
                const float* s = f2g + inBase + (size_t)((kc0) + cp2 * 2) * HW_ \
                                 + (size_t)gh * W_ + gw2;                       \
                A0[i] = *(const f32x4v*)s;                                      \
                A1[i] = *(const f32x4v*)(s + HW_);                              \
            } else {                                                            \
                A0[i] = (f32x4v)0.f;                                            \
                A1[i] = (f32x4v)0.f;                                            \
            }                                                                   \
        }                                                                       \
        const float* s = src1 + (size_t)((kc0) + cp1 * 2) * HW_;                \
        B0 = *(const f32x4v*)s;                                                 \
        B1 = *(const f32x4v*)(s + HW_);                                         \
    }

#define PACK_WRITE(buf)                                                         \
    {                                                                           \
        char* w2 = (char*)&f2s[(buf)][0];                                       \
        char* w1 = (char*)&f1s[(buf)][0];                                       \
        _Pragma("unroll")                                                       \
        for (int i = 0; i < 4; ++i) {                                           \
            int r = i * 4 + rq;                                                 \
            _Pragma("unroll")                                                   \
            for (int j = 0; j < 4; ++j) {                                       \
                int px = r * 32 + g2 * 4 + j;                                   \
                *(unsigned int*)(w2 + swz(px, cp2 * 4)) =                       \
                    cvt_pk_bf16(A0[i][j], A1[i][j]);                            \
            }                                                                   \
        }                                                                       \
        _Pragma("unroll")                                                       \
        for (int j = 0; j < 4; ++j) {                                           \
            int px = r1 * 16 + g1 * 4 + j;                                      \
            *(unsigned int*)(w1 + swz(px, cp1 * 4)) = cvt_pk_bf16(B0[j], B1[j]);\
        }                                                                       \
    }

#define MFMA_PHASE(buf)                                                         \
    {                                                                           \
        const char* r2 = (const char*)&f2s[(buf)][0];                           \
        const char* r1p = (const char*)&f1s[(buf)][0];                          \
        bf16x8 af = *(const bf16x8*)(r1p + aOff);                               \
        _Pragma("unroll")                                                       \
        for (int dy = 0; dy < 9; ++dy) {                                        \
            int pb = (wave + dy) * WCOL + col;                                  \
            bf16x8 b0 = *(const bf16x8*)(r2 + swz(pb, quad * 16));              \
            bf16x8 b1 = *(const bf16x8*)(r2 + swz(pb + 16, quad * 16));         \
            acc[dy][0] = __builtin_amdgcn_mfma_f32_16x16x32_bf16(af, b0, acc[dy][0], 0, 0, 0); \
            acc[dy][1] = __builtin_amdgcn_mfma_f32_16x16x32_bf16(af, b1, acc[dy][1], 0, 0, 0); \
        }                                                                       \
    }

#define NORM_PHASE(buf)                                                         \
    {                                                                           \
        const char* r2 = (const char*)&f2s[(buf)][0];                           \
        const char* r1p = (const char*)&f1s[(buf)][0];                          \
        _Pragma("unroll")                                                       \
        for (int j = 0; j < 4; ++j) {                                           \
            u32x4 v = *(const u32x4*)(r2 + swz(tid, j * 16));                   \
            dot2_sq(v[0], ss2); dot2_sq(v[1], ss2);                             \
            dot2_sq(v[2], ss2); dot2_sq(v[3], ss2);                             \
        }                                                                       \
        u32x4 v = *(const u32x4*)(r1p + swz(tid >> 2, (tid & 3) * 16));         \
        dot2_sq(v[0], ss1); dot2_sq(v[1], ss1);                                 \
        dot2_sq(v[2], ss1); dot2_sq(v[3], ss1);                                 \
    }

    // ---- prologue: stage chunk 0 into buf0, issue chunk-1 loads ----
    ISSUE_LOADS(0);
    PACK_WRITE(0);
    ISSUE_LOADS(KC);
    BARRIER();

    // ---- main: one barrier per chunk; loads fly across barriers ----
#pragma unroll
    for (int k = 0; k < NCHUNK; ++k) {
        const int bk = k & 1;
        MFMA_PHASE(bk);
        if (k < NCHUNK - 1) {
            PACK_WRITE(bk ^ 1);            // consumes prefetch regs (WAR before re-issue)
            if (k < NCHUNK - 2) ISSUE_LOADS((k + 2) * KC);
            NORM_PHASE(bk);
        } else {
            NORM_PHASE(bk);
            invn2[tid] = 1.f / fmaxf(sqrtf(ss2), 1e-12f);
            float t1 = ss1 + __shfl_xor(ss1, 1);
            t1 += __shfl_xor(t1, 2);
            if ((tid & 3) == 0) invn1[tid >> 2] = 1.f / fmaxf(sqrtf(t1), 1e-12f);
        }
        BARRIER();
    }

    // ---- epilogue: extract band, rescale, leaky-relu, store ----
    const int hOut = h0 + wave;
    float* outB = out + (size_t)b * ND * HW_ + (size_t)hOut * W_;
    const float scale = 1.f / (float)C_;

#pragma unroll
    for (int dy = 0; dy < 9; ++dy) {
        int hr = wave + dy;
#pragma unroll
        for (int t = 0; t < 2; ++t) {
            float i2 = invn2[hr * WCOL + t * 16 + col];
#pragma unroll
            for (int r = 0; r < 4; ++r) {
                int row = quad * 4 + r;
                int dx = t * 16 + col - row;
                if (dx >= 0 && dx <= 8) {
                    float v = acc[dy][t][r] * invn1[wave * 16 + row] * i2 * scale;
                    v = (v >= 0.f) ? v : 0.1f * v;
                    outB[(size_t)(dy * 9 + dx) * HW_ + (w0 + row)] = v;
                }
            }
        }
    }
#undef ISSUE_LOADS
#undef PACK_WRITE
#undef MFMA_PHASE
#undef NORM_PHASE
}

extern "C" void kernel_launch(void* const* d_in, const int* in_sizes, int n_in,
                              void* d_out, int out_size, void* d_ws, size_t ws_size,
                              hipStream_t stream) {
    const float* f1 = (const float*)d_in[0];
    const float* f2 = (const float*)d_in[1];
    float* out = (float*)d_out;
    dim3 grid(W_ / TW, H_ / TH, B_);   // 16 x 16 x 4 = 1024 blocks
    corr81_kernel<<<grid, NTHREADS, 0, stream>>>(f1, f2, out);
}